// Round 7
// baseline (549.391 us; speedup 1.0000x reference)
//
#include <hip/hip_runtime.h>
#include <hip/hip_bf16.h>
#include <math.h>

#define NB 4
#define NN 4096
#define UU 512

using short8   = __attribute__((ext_vector_type(8))) short;
using bf16x8   = __attribute__((ext_vector_type(8))) __bf16;
using floatx4  = __attribute__((ext_vector_type(4))) float;
using floatx16 = __attribute__((ext_vector_type(16))) float;

__device__ __forceinline__ floatx4 mfma16(short8 a, short8 b, floatx4 c) {
    return __builtin_amdgcn_mfma_f32_16x16x32_bf16(
        __builtin_bit_cast(bf16x8, a), __builtin_bit_cast(bf16x8, b), c, 0, 0, 0);
}
__device__ __forceinline__ floatx16 mfma32(short8 a, short8 b, floatx16 c) {
    return __builtin_amdgcn_mfma_f32_32x32x16_bf16(
        __builtin_bit_cast(bf16x8, a), __builtin_bit_cast(bf16x8, b), c, 0, 0, 0);
}

__device__ __forceinline__ unsigned short f2bf(float f) {
    union { float f; unsigned u; } v; v.f = f;
    return (unsigned short)((v.u + 0x7fffu + ((v.u >> 16) & 1u)) >> 16);
}

#define GLL16(gp, lp) __builtin_amdgcn_global_load_lds( \
    (const __attribute__((address_space(1))) void*)(gp), \
    (__attribute__((address_space(3))) void*)(lp), 16, 0, 0)

// ---------------------------------------------------------------- converts
__global__ void __launch_bounds__(256) k_cvt_x(const float* __restrict__ x,
                                               unsigned short* __restrict__ xb) {
    int i = (blockIdx.x * 256 + threadIdx.x) * 4;
    float4 v = *(const float4*)(x + i);
    ushort4 o;
    o.x = f2bf(v.x); o.y = f2bf(v.y); o.z = f2bf(v.z); o.w = f2bf(v.w);
    *(ushort4*)(xb + i) = o;
}

__global__ void __launch_bounds__(256) k_cvt_w4(
    const float* __restrict__ Wq, const float* __restrict__ Wk,
    const float* __restrict__ Wv, const float* __restrict__ Wp,
    unsigned short* __restrict__ WTbase) {
    const int z = blockIdx.y;
    const float* W = (z == 0) ? Wq : (z == 1) ? Wk : (z == 2) ? Wv : Wp;
    int idx = blockIdx.x * 256 + threadIdx.x;
    int n = idx >> 9, k = idx & 511;
    WTbase[(size_t)z * 262144 + idx] = f2bf(W[k * 512 + n]);
}

// ---------------------------------------------------------------- QKV proj
// z=0: Q row-major [b*N][U]
// z=1: K8 layout [b][d>>3][key][d&7]
// z=2: V8p layout [b][keyp>>3][d][keyp&7], keyp = key-within-16 permuted
//      [0,1,2,3,8,9,10,11,4,5,6,7,12,13,14,15] so PV B-frags match the
//      S^T C-layout A-frag key order.
__global__ void __launch_bounds__(256, 2) k_proj(
    const unsigned short* __restrict__ Xb,
    const unsigned short* __restrict__ WqT, const unsigned short* __restrict__ WkT,
    const unsigned short* __restrict__ WvT,
    const float* __restrict__ bq, const float* __restrict__ bk, const float* __restrict__ bv,
    unsigned short* __restrict__ Q, unsigned short* __restrict__ K8,
    unsigned short* __restrict__ V8)
{
    __shared__ __align__(16) unsigned short As[128 * 32];
    __shared__ __align__(16) unsigned short Bs[128 * 32];
    const int z = blockIdx.z;
    const unsigned short* WT = (z == 0) ? WqT : (z == 1) ? WkT : WvT;
    const float* bias = (z == 0) ? bq : (z == 1) ? bk : bv;
    const int t = threadIdx.x, wave = t >> 6, lane = t & 63;
    const int quad = lane >> 4, l16 = lane & 15;
    const int m0 = blockIdx.x * 128, n0 = blockIdx.y * 128;
    const int wm = wave >> 1, wn = wave & 1;

    const int srow = wave * 32 + (lane >> 2);
    const int scol = (lane & 3) * 8;
    const unsigned short* gA = Xb + (size_t)(m0 + srow) * UU + scol;
    const unsigned short* gB = WT + (size_t)(n0 + srow) * UU + scol;
    unsigned short* lA = As + wave * 1024;
    unsigned short* lB = Bs + wave * 1024;

    floatx4 acc[4][4] = {};

    for (int k0 = 0; k0 < UU; k0 += 32) {
        GLL16(gA + k0, lA);
        GLL16(gA + k0 + 16 * UU, lA + 512);
        GLL16(gB + k0, lB);
        GLL16(gB + k0 + 16 * UU, lB + 512);
        __syncthreads();
        short8 a[4], b[4];
        #pragma unroll
        for (int i = 0; i < 4; i++)
            a[i] = *(const short8*)(As + (wm * 64 + i * 16 + l16) * 32 + quad * 8);
        #pragma unroll
        for (int j = 0; j < 4; j++)
            b[j] = *(const short8*)(Bs + (wn * 64 + j * 16 + l16) * 32 + quad * 8);
        #pragma unroll
        for (int i = 0; i < 4; i++)
            #pragma unroll
            for (int j = 0; j < 4; j++)
                acc[i][j] = mfma16(a[i], b[j], acc[i][j]);
        __syncthreads();
    }

    #pragma unroll
    for (int j = 0; j < 4; j++) {
        const int n = n0 + wn * 64 + j * 16 + l16;
        const float bv_ = bias[n];
        #pragma unroll
        for (int i = 0; i < 4; i++) {
            const int mb = m0 + wm * 64 + i * 16 + quad * 4;
            const int bb = mb >> 12, tok = mb & (NN - 1);
            if (z == 0) {
                #pragma unroll
                for (int r = 0; r < 4; r++)
                    Q[(size_t)(mb + r) * UU + n] = f2bf(acc[i][j][r] + bv_);
            } else if (z == 1) {
                const size_t base = (size_t)bb * NN * UU + (size_t)(n >> 3) * (NN * 8)
                                  + (size_t)tok * 8 + (n & 7);
                #pragma unroll
                for (int r = 0; r < 4; r++)
                    K8[base + (size_t)r * 8] = f2bf(acc[i][j][r] + bv_);
            } else {
                const int t4 = tok & 15;   // tok % 4 == 0
                const int p4 = (t4 & 3) | ((t4 & 8) >> 1) | ((t4 & 4) << 1);
                const int tokp = (tok & ~15) | p4;
                ushort4 o;
                o.x = f2bf(acc[i][j][0] + bv_);
                o.y = f2bf(acc[i][j][1] + bv_);
                o.z = f2bf(acc[i][j][2] + bv_);
                o.w = f2bf(acc[i][j][3] + bv_);
                *(ushort4*)(V8 + (size_t)bb * NN * UU + (size_t)(tokp >> 3) * (UU * 8)
                            + (size_t)n * 8 + (tokp & 7)) = o;
            }
        }
    }
}

// ---------------------------------------------------------------- flash attention
// Max-free softmax. 8 waves (512 thr), BM=64 q-rows/block, BN=256 keys/iter,
// 16 iterations, ONE barrier per iteration.
// Phase 1 (wave-local): S^T = K.Q^T for wave's 32-key chunk, both 32-row
//   q-subtiles, full 512 dims (64 mfma32). p = exp2(s*c) in C-layout regs;
//   lane row-sums accumulate (col=l31=qrow!); A-frags are a register repack
//   (C reg r=8s+j -> A slot j, key order matches permuted V8p); relay via LDS
//   (16B/lane, conflict-free).
// Phase 2: PV for wave's 64-dim slice over all 256 keys (64 mfma32), V frags
//   direct from L2 (temporal reuse across blocks).
__global__ void __launch_bounds__(512, 2) k_flash(
    const unsigned short* __restrict__ Q,
    const unsigned short* __restrict__ K8,
    const unsigned short* __restrict__ V8p,
    unsigned short* __restrict__ ctx)
{
    __shared__ __align__(16) unsigned short Pbuf[2 * 2 * 8 * 2 * 64 * 8]; // 64 KB
    __shared__ float lred[2][8][32];
    __shared__ float ltot[64];

    // XCD swizzle: batch pinned to an XCD pair (assumes round-robin id%8)
    const int id = blockIdx.x;
    const int b = (id & 7) >> 1;
    const int qg = ((id >> 3) << 1) | (id & 1);
    const int q0 = qg * 64;

    const int t = threadIdx.x, w = t >> 6, lane = t & 63;
    const int l31 = lane & 31, ah = lane >> 5;

    const unsigned short* K8b = K8 + (size_t)b * NN * UU + (size_t)ah * (NN * 8);
    const unsigned short* V8b = V8p + (size_t)b * NN * UU
                              + (size_t)ah * (UU * 8) + (size_t)(w * 64 + l31) * 8;
    const unsigned short* Qb0 = Q + (size_t)(b * NN + q0 + l31) * UU + ah * 8;
    const unsigned short* Qb1 = Qb0 + 32 * UU;
    const float sscale = 0.04419417382415922f * 1.4426950408889634f; // 1/sqrt(512)*log2e

    floatx16 o[2][2] = {};
    float lsum0 = 0.f, lsum1 = 0.f;
    int buf = 0;

    for (int kt = 0; kt < NN; kt += 256) {
        // ---- phase 1: S^T (m=key, n=qrow), wave's 32 keys, 64 q-rows
        const unsigned short* Kp = K8b + (size_t)(kt + w * 32 + l31) * 8;
        floatx16 s0 = {}, s1 = {};
        #pragma unroll
        for (int ds = 0; ds < 32; ds++) {
            short8 kf = *(const short8*)(Kp + (size_t)ds * 2 * (NN * 8));
            short8 qf0 = *(const short8*)(Qb0 + ds * 16);
            short8 qf1 = *(const short8*)(Qb1 + ds * 16);
            s0 = mfma32(kf, qf0, s0);
            s1 = mfma32(kf, qf1, s1);
        }
        // exp2, row-sum accumulate, pack A-frags (C reg r=8s+j -> slot j)
        short8 f00, f01, f10, f11;
        #pragma unroll
        for (int r = 0; r < 8; r++) {
            float p0 = exp2f(s0[r] * sscale);
            float p1 = exp2f(s1[r] * sscale);
            lsum0 += p0; lsum1 += p1;
            f00[r] = (short)f2bf(p0); f10[r] = (short)f2bf(p1);
        }
        #pragma unroll
        for (int r = 8; r < 16; r++) {
            float p0 = exp2f(s0[r] * sscale);
            float p1 = exp2f(s1[r] * sscale);
            lsum0 += p0; lsum1 += p1;
            f01[r - 8] = (short)f2bf(p0); f11[r - 8] = (short)f2bf(p1);
        }
        {
            unsigned short* pb = Pbuf + ((((buf * 2 + 0) * 8 + w) * 2) * 64 + lane) * 8;
            *(short8*)(pb) = f00;
            *(short8*)(pb + 64 * 8) = f01;
            unsigned short* pb1 = Pbuf + ((((buf * 2 + 1) * 8 + w) * 2) * 64 + lane) * 8;
            *(short8*)(pb1) = f10;
            *(short8*)(pb1 + 64 * 8) = f11;
        }
        __syncthreads();   // the ONLY barrier per 256 keys

        // ---- phase 2: PV for d-slice w*64..+63, all 256 keys
        const unsigned short* Vk = V8b + (size_t)(kt >> 3) * (UU * 8);
        #pragma unroll
        for (int c = 0; c < 8; c++) {
            #pragma unroll
            for (int st = 0; st < 2; st++) {
                const unsigned short* pbase = Pbuf + (((buf * 2) * 8 + c) * 2 + st) * 64 * 8;
                short8 pa0 = *(const short8*)(pbase + lane * 8);
                short8 pa1 = *(const short8*)(pbase + 16 * 64 * 8 + lane * 8);
                const unsigned short* vv = Vk + (size_t)(c * 4 + st * 2) * (UU * 8);
                short8 vf0 = *(const short8*)(vv);
                short8 vf1 = *(const short8*)(vv + 32 * 8);   // dt=1 (+32 dims)
                o[0][0] = mfma32(pa0, vf0, o[0][0]);
                o[1][0] = mfma32(pa1, vf0, o[1][0]);
                o[0][1] = mfma32(pa0, vf1, o[0][1]);
                o[1][1] = mfma32(pa1, vf1, o[1][1]);
            }
        }
        buf ^= 1;
    }

    // ---- epilogue: reduce row sums (over ah halves and 8 wave-chunks)
    lsum0 += __shfl_xor(lsum0, 32);
    lsum1 += __shfl_xor(lsum1, 32);
    if (lane < 32) { lred[0][w][lane] = lsum0; lred[1][w][lane] = lsum1; }
    __syncthreads();
    if (t < 64) {
        const int s2 = t >> 5, rr = t & 31;
        float s = 0.f;
        #pragma unroll
        for (int u = 0; u < 8; u++) s += lred[s2][u][rr];
        ltot[t] = 1.f / s;
    }
    __syncthreads();

    #pragma unroll
    for (int s2 = 0; s2 < 2; s2++) {
        #pragma unroll
        for (int dt = 0; dt < 2; dt++) {
            #pragma unroll
            for (int r = 0; r < 16; r++) {
                const int row32 = (r & 3) + 8 * (r >> 2) + 4 * ah;
                const float linv = ltot[s2 * 32 + row32];
                const int row = q0 + s2 * 32 + row32;
                const int d = w * 64 + dt * 32 + l31;
                ctx[(size_t)(b * NN + row) * UU + d] = f2bf(o[s2][dt][r] * linv);
            }
        }
    }
}

// ---------------------------------------------------------------- out proj + residual
__global__ void __launch_bounds__(256, 2) k_out(
    const unsigned short* __restrict__ Cx,
    const unsigned short* __restrict__ WpT,
    const float* __restrict__ bp,
    const float* __restrict__ x,
    float* __restrict__ out)
{
    __shared__ __align__(16) unsigned short As[128 * 32];
    __shared__ __align__(16) unsigned short Bs[128 * 32];
    const int t = threadIdx.x, wave = t >> 6, lane = t & 63;
    const int quad = lane >> 4, l16 = lane & 15;
    const int m0 = blockIdx.x * 128, n0 = blockIdx.y * 128;
    const int wm = wave >> 1, wn = wave & 1;
    const int srow = wave * 32 + (lane >> 2);
    const int scol = (lane & 3) * 8;
    const unsigned short* gA = Cx + (size_t)(m0 + srow) * UU + scol;
    const unsigned short* gB = WpT + (size_t)(n0 + srow) * UU + scol;
    unsigned short* lA = As + wave * 1024;
    unsigned short* lB = Bs + wave * 1024;

    floatx4 acc[4][4] = {};

    for (int k0 = 0; k0 < UU; k0 += 32) {
        GLL16(gA + k0, lA);
        GLL16(gA + k0 + 16 * UU, lA + 512);
        GLL16(gB + k0, lB);
        GLL16(gB + k0 + 16 * UU, lB + 512);
        __syncthreads();
        short8 a[4], b[4];
        #pragma unroll
        for (int i = 0; i < 4; i++)
            a[i] = *(const short8*)(As + (wm * 64 + i * 16 + l16) * 32 + quad * 8);
        #pragma unroll
        for (int j = 0; j < 4; j++)
            b[j] = *(const short8*)(Bs + (wn * 64 + j * 16 + l16) * 32 + quad * 8);
        #pragma unroll
        for (int i = 0; i < 4; i++)
            #pragma unroll
            for (int j = 0; j < 4; j++)
                acc[i][j] = mfma16(a[i], b[j], acc[i][j]);
        __syncthreads();
    }

    #pragma unroll
    for (int j = 0; j < 4; j++) {
        const int n = n0 + wn * 64 + j * 16 + l16;
        const float bv_ = bp[n];
        #pragma unroll
        for (int i = 0; i < 4; i++) {
            const int mb = m0 + wm * 64 + i * 16 + quad * 4;
            #pragma unroll
            for (int r = 0; r < 4; r++) {
                const size_t idx = (size_t)(mb + r) * UU + n;
                out[idx] = acc[i][j][r] + bv_ + x[idx];
            }
        }
    }
}

// ---------------------------------------------------------------- launch
extern "C" void kernel_launch(void* const* d_in, const int* in_sizes, int n_in,
                              void* d_out, int out_size, void* d_ws, size_t ws_size,
                              hipStream_t stream)
{
    const float* x  = (const float*)d_in[0];
    const float* Wq = (const float*)d_in[1];
    const float* bq = (const float*)d_in[2];
    const float* Wk = (const float*)d_in[3];
    const float* bk = (const float*)d_in[4];
    const float* Wv = (const float*)d_in[5];
    const float* bv = (const float*)d_in[6];
    const float* Wp = (const float*)d_in[7];
    const float* bp = (const float*)d_in[8];
    float* out = (float*)d_out;

    char* ws = (char*)d_ws;
    unsigned short* Xb  = (unsigned short*)(ws);              // 16 MB  bf16 x
    unsigned short* WTb = (unsigned short*)(ws + 16777216);   // 4 x 512 KB contiguous
    unsigned short* WqT = WTb;
    unsigned short* WkT = WTb + 262144;
    unsigned short* WvT = WTb + 524288;
    unsigned short* WpT = WTb + 786432;
    unsigned short* Qm  = (unsigned short*)(ws + 18874368);   // 16 MB [b*N][U]
    unsigned short* K8m = (unsigned short*)(ws + 35651584);   // 16 MB [b][d>>3][key][d&7]
    unsigned short* V8m = (unsigned short*)(ws + 52428800);   // 16 MB [b][keyp>>3][d][keyp&7]
    unsigned short* Cx  = (unsigned short*)(ws + 69206016);   // 16 MB [b*N][U]

    hipLaunchKernelGGL(k_cvt_x, dim3(8192), dim3(256), 0, stream, x, Xb);
    hipLaunchKernelGGL(k_cvt_w4, dim3(1024, 4), dim3(256), 0, stream, Wq, Wk, Wv, Wp, WTb);
    hipLaunchKernelGGL(k_proj, dim3(128, 4, 3), dim3(256), 0, stream,
                       Xb, WqT, WkT, WvT, bq, bk, bv, Qm, K8m, V8m);
    hipLaunchKernelGGL(k_flash, dim3(256), dim3(512), 0, stream, Qm, K8m, V8m, Cx);
    hipLaunchKernelGGL(k_out, dim3(128, 4), dim3(256), 0, stream, Cx, WpT, bp, x, out);
}